// Round 1
// 1134.801 us; speedup vs baseline: 1.0764x; 1.0764x over previous
//
#include <hip/hip_runtime.h>

// Problem constants (fixed by setup_inputs)
#define N_BATCH 4
#define OC 128
#define ICPG 16
#define GROUPS 8
#define H 256
#define W 256
#define TR 16   // base rows per block (4 waves x 4 rows)
#define RPW 4   // base rows per wave

// Effective fused weights: [o][c][r*3+s][phase(pi*2+pj)]  -> 128*16*9*4 floats
__device__ float g_weff[OC * ICPG * 9 * 4];

// y[n][o][2bi+pi][2bj+pj] = sum_{c,r,s} Weff[o][c][r][s][pi*2+pj] * x[n][g*16+c][bi+r-1][bj+s-1]
// Weff[o][c][r][s][ph] = 4 * sum_{dy,dx} w[o][c][dy][dx] * f[pi+dy-2(r-1)] * f[pj+dx-2(s-1)]

__global__ void prep_weff(const float* __restrict__ w, const float* __restrict__ f) {
    int t = blockIdx.x * 256 + threadIdx.x;   // t = o*16 + c
    if (t >= OC * ICPG) return;
    float wl[9];
#pragma unroll
    for (int i = 0; i < 9; i++) wl[i] = w[t * 9 + i];
    float fl[4];
#pragma unroll
    for (int i = 0; i < 4; i++) fl[i] = f[i];
    float* out = g_weff + t * 36;
#pragma unroll
    for (int r = 0; r < 3; r++) {
#pragma unroll
        for (int s = 0; s < 3; s++) {
#pragma unroll
            for (int pi = 0; pi < 2; pi++) {
#pragma unroll
                for (int pj = 0; pj < 2; pj++) {
                    float acc = 0.f;
#pragma unroll
                    for (int dy = 0; dy < 3; dy++) {
                        int fy = pi + dy - 2 * (r - 1);
                        if (fy < 0 || fy > 3) continue;
#pragma unroll
                        for (int dx = 0; dx < 3; dx++) {
                            int fx = pj + dx - 2 * (s - 1);
                            if (fx < 0 || fx > 3) continue;
                            acc += wl[dy * 3 + dx] * fl[fy] * fl[fx];
                        }
                    }
                    out[(r * 3 + s) * 4 + pi * 2 + pj] = 4.f * acc;
                }
            }
        }
    }
}

// Each lane owns 4 base columns (64 lanes x 4 = 256 cols). Per input row per
// channel: one aligned float4 load + 2 shuffles for the halo -> 48 FMAs.
// Each wave owns RPW consecutive base rows; 16 accumulators per thread.
__global__ __launch_bounds__(256) void conv_fused(const float* __restrict__ x,
                                                  float* __restrict__ y) {
    const int lane = threadIdx.x & 63;
    const int wid  = threadIdx.x >> 6;     // 0..3
    const int rowt = blockIdx.x;           // 0..15
    const int o    = blockIdx.y;           // 0..127
    const int n    = blockIdx.z;           // 0..3
    const int g    = o >> 4;

    const int bj4 = lane << 2;             // first base col of this lane
    const float* xb = x + ((size_t)(n * OC + g * ICPG)) * (H * W);
    const float* wp = g_weff + (size_t)o * ICPG * 36;

    const int bi0 = rowt * TR + wid * RPW;

#pragma unroll 1
    for (int rr = 0; rr < RPW; rr++) {
        const int bi = bi0 + rr;

        float acc[4][4];                   // [col j][phase ph]
#pragma unroll
        for (int j = 0; j < 4; j++)
#pragma unroll
            for (int ph = 0; ph < 4; ph++) acc[j][ph] = 0.f;

#pragma unroll 2
        for (int c = 0; c < ICPG; c++) {
            const float* xc = xb + (size_t)c * (H * W);
            const float* wc = wp + c * 36;
#pragma unroll
            for (int r = 0; r < 3; r++) {
                const int iy = bi + r - 1;
                float4 v;
                if ((unsigned)iy < (unsigned)H) {
                    v = *(const float4*)(xc + (size_t)iy * W + bj4);
                } else {
                    v = make_float4(0.f, 0.f, 0.f, 0.f);
                }
                float xl = __shfl_up(v.w, 1);
                if (lane == 0) xl = 0.f;            // col -1
                float xr = __shfl_down(v.x, 1);
                if (lane == 63) xr = 0.f;           // col 256
                const float xw[6] = {xl, v.x, v.y, v.z, v.w, xr};
#pragma unroll
                for (int s = 0; s < 3; s++) {
                    const float4 wv = *(const float4*)(wc + (r * 3 + s) * 4);
#pragma unroll
                    for (int j = 0; j < 4; j++) {
                        const float xv = xw[j + s];
                        acc[j][0] += xv * wv.x;
                        acc[j][1] += xv * wv.y;
                        acc[j][2] += xv * wv.z;
                        acc[j][3] += xv * wv.w;
                    }
                }
            }
        }

        // Write 2 output rows x 8 consecutive cols (2 float4 each).
        float* yb = y + (((size_t)(n * OC + o) * (2 * H)) + 2 * bi) * (2 * W) + 2 * bj4;
        *(float4*)(yb)             = make_float4(acc[0][0], acc[0][1], acc[1][0], acc[1][1]);
        *(float4*)(yb + 4)         = make_float4(acc[2][0], acc[2][1], acc[3][0], acc[3][1]);
        *(float4*)(yb + 2 * W)     = make_float4(acc[0][2], acc[0][3], acc[1][2], acc[1][3]);
        *(float4*)(yb + 2 * W + 4) = make_float4(acc[2][2], acc[2][3], acc[3][2], acc[3][3]);
    }
}

extern "C" void kernel_launch(void* const* d_in, const int* in_sizes, int n_in,
                              void* d_out, int out_size, void* d_ws, size_t ws_size,
                              hipStream_t stream) {
    const float* x = (const float*)d_in[0];
    const float* f = (const float*)d_in[1];
    const float* w = (const float*)d_in[2];
    float* y = (float*)d_out;

    hipLaunchKernelGGL(prep_weff, dim3(8), dim3(256), 0, stream, w, f);

    dim3 grid(H / TR, OC, N_BATCH);
    hipLaunchKernelGGL(conv_fused, grid, dim3(256), 0, stream, x, y);
}